// Round 1
// baseline (276.549 us; speedup 1.0000x reference)
//
#include <hip/hip_runtime.h>
#include <math.h>

#define PP   7
#define NDIR 49
#define CIN  3
#define KK   147      // CIN * 49
#define EE   384
#define HH   224
#define WW   224
#define GG   16       // patches per block
#define TB   384      // threads per block (one per output e)

// ---- pre-kernel: transpose proj_w (E,K) row-major -> pwT (K,E) for coalesced reads
__global__ void transpose_pw_kernel(const float* __restrict__ pw, float* __restrict__ pwT) {
    int idx = blockIdx.x * blockDim.x + threadIdx.x;
    if (idx < EE * KK) {
        int e = idx / KK;
        int k = idx - e * KK;
        pwT[k * EE + e] = pw[idx];
    }
}

__device__ __forceinline__ float sigmoidf_(float v) {
    return 1.0f / (1.0f + expf(-v));
}

__launch_bounds__(TB)
__global__ void metric_patch_kernel(const float* __restrict__ x,
                                    const float* __restrict__ mw,
                                    const float* __restrict__ mb,
                                    const float* __restrict__ pwT,
                                    const float* __restrict__ pb,
                                    float* __restrict__ out) {
    __shared__ float strip[21][112];                 // x patch strip: [c*7+i][col]
    __shared__ float mws[7 * KK];                    // metric_w [o][k]
    __shared__ float params_s[GG][8];
    __shared__ float der[GG][8];                     // M00,M01,M11,w0,w1
    __shared__ __align__(16) float samp[KK][GG];     // sampled, k-major, g inner

    const int t   = threadIdx.x;
    const int blk = blockIdx.x;
    const int b   = blk >> 6;          // 64 blocks per image (32 hp rows x 2 half-rows)
    const int rem = blk & 63;
    const int hp  = rem >> 1;
    const int wp0 = (rem & 1) * GG;

    const float* xb = x + (size_t)b * (CIN * HH * WW);

    // ---- stage x strip (21 rows x 112 cols, coalesced) + metric_w
    for (int idx = t; idx < 21 * 112; idx += TB) {
        int r = idx / 112;
        int col = idx - r * 112;
        int c = r / 7;
        int i = r - c * 7;
        strip[r][col] = xb[c * (HH * WW) + (hp * PP + i) * WW + wp0 * PP + col];
    }
    for (int idx = t; idx < 7 * KK; idx += TB) {
        mws[idx] = mw[idx];
    }
    __syncthreads();

    // ---- metric conv: params[g][o]
    if (t < GG * 7) {
        int g = t / 7;
        int o = t - g * 7;
        float acc = mb[o];
        const float* wrow = &mws[o * KK];
        int k = 0;
        for (int c = 0; c < CIN; ++c)
            for (int i = 0; i < PP; ++i) {
                const float* srow = &strip[c * PP + i][g * PP];
                #pragma unroll
                for (int j = 0; j < PP; ++j, ++k)
                    acc = fmaf(srow[j], wrow[k], acc);
            }
        params_s[g][o] = acc;
    }
    __syncthreads();

    // ---- derived per-patch quantities: M (symmetric 2x2) and drift w
    if (t < GG) {
        float p0 = params_s[t][0], p1 = params_s[t][1];
        float p2 = params_s[t][2], p3 = params_s[t][3];
        float p4 = params_s[t][4];
        float p5 = params_s[t][5], p6 = params_s[t][6];
        float nrm = sqrtf(p0 * p0 + p1 * p1);
        float inv = 1.0f / fmaxf(nrm, 1e-12f);
        float v0 = p0 * inv, v1 = p1 * inv;
        float e0 = 2.0f * sigmoidf_(p2);
        float e1 = 2.0f * sigmoidf_(p3);
        float sc = 0.5f + 1.5f * sigmoidf_(p4);
        e0 *= sc; e1 *= sc;
        der[t][0] = e0 * v0 * v0 + e1 * v1 * v1;     // M00
        der[t][1] = (e0 - e1) * v0 * v1;             // M01 (= M10)
        der[t][2] = e0 * v1 * v1 + e1 * v0 * v0;     // M11
        float wn  = sqrtf(p5 * p5 + p6 * p6);
        float wsc = 0.5f * sigmoidf_(wn);            // (1-EPS_W)*sigmoid(|w|)
        der[t][3] = p5 * wsc;                        // w0
        der[t][4] = p6 * wsc;                        // w1
    }
    __syncthreads();

    // ---- positions + bilinear gather into samp[k][g]
    // key algebra: py = hp*7 + 3 + u_y * r ; px = wp*7 + 3 + u_x * r (i,j cancel)
    for (int item = t; item < GG * NDIR; item += TB) {
        int g = item / NDIR;
        int n = item - g * NDIR;
        float u0, u1, s;
        if (n == 0)      { u0 = 1.0f; u1 = 0.0f; s = 0.0f; }
        else if (n < 9)  { float th = (float)(n - 1)  * 0.78539816339744831f; u0 = cosf(th); u1 = sinf(th); s = 0.33333334f; }
        else if (n < 25) { float th = (float)(n - 9)  * 0.39269908169872414f; u0 = cosf(th); u1 = sinf(th); s = 0.66666669f; }
        else             { float th = (float)(n - 25) * 0.26179938779914941f; u0 = cosf(th); u1 = sinf(th); s = 1.0f; }
        float M00 = der[g][0], M01 = der[g][1], M11 = der[g][2];
        float w0 = der[g][3], w1 = der[g][4];
        float quad  = u0 * u0 * M00 + 2.0f * u0 * u1 * M01 + u1 * u1 * M11;
        float drift = w0 * u0 + w1 * u1;
        float F = sqrtf(quad + 1e-6f) + drift;
        float r = s / (F + 1e-6f);
        float py = (float)(hp * PP + 3) + u1 * r;
        float px = (float)((wp0 + g) * PP + 3) + u0 * r;
        float y0f = floorf(py), x0f = floorf(px);
        float y1f = y0f + 1.0f, x1f = x0f + 1.0f;
        float wy = py - y0f, wx = px - x0f;
        bool vy0 = (y0f >= 0.0f) && (y0f <= (float)(HH - 1));
        bool vy1 = (y1f >= 0.0f) && (y1f <= (float)(HH - 1));
        bool vx0 = (x0f >= 0.0f) && (x0f <= (float)(WW - 1));
        bool vx1 = (x1f >= 0.0f) && (x1f <= (float)(WW - 1));
        int iy0 = (int)fminf(fmaxf(y0f, 0.0f), (float)(HH - 1));
        int iy1 = (int)fminf(fmaxf(y1f, 0.0f), (float)(HH - 1));
        int ix0 = (int)fminf(fmaxf(x0f, 0.0f), (float)(WW - 1));
        int ix1 = (int)fminf(fmaxf(x1f, 0.0f), (float)(WW - 1));
        float w00 = (1.0f - wy) * (1.0f - wx);
        float w01 = (1.0f - wy) * wx;
        float w10 = wy * (1.0f - wx);
        float w11 = wy * wx;
        #pragma unroll
        for (int c = 0; c < CIN; ++c) {
            const float* xc = xb + c * (HH * WW);
            float v00 = (vy0 && vx0) ? xc[iy0 * WW + ix0] : 0.0f;
            float v01 = (vy0 && vx1) ? xc[iy0 * WW + ix1] : 0.0f;
            float v10 = (vy1 && vx0) ? xc[iy1 * WW + ix0] : 0.0f;
            float v11 = (vy1 && vx1) ? xc[iy1 * WW + ix1] : 0.0f;
            samp[c * NDIR + n][g] = v00 * w00 + v01 * w01 + v10 * w10 + v11 * w11;
        }
    }
    __syncthreads();

    // ---- projection GEMM: thread t owns output channel e=t, acc over 16 patches
    float acc[GG];
    #pragma unroll
    for (int g = 0; g < GG; ++g) acc[g] = 0.0f;
    for (int k = 0; k < KK; ++k) {
        float wv = pwT[k * EE + t];
        const float4* row = (const float4*)(&samp[k][0]);
        #pragma unroll
        for (int q = 0; q < 4; ++q) {
            float4 sv = row[q];
            acc[4 * q + 0] = fmaf(sv.x, wv, acc[4 * q + 0]);
            acc[4 * q + 1] = fmaf(sv.y, wv, acc[4 * q + 1]);
            acc[4 * q + 2] = fmaf(sv.z, wv, acc[4 * q + 2]);
            acc[4 * q + 3] = fmaf(sv.w, wv, acc[4 * q + 3]);
        }
    }
    float bias = pb[t];
    size_t m0 = (size_t)blk * GG;
    #pragma unroll
    for (int g = 0; g < GG; ++g) {
        out[(m0 + g) * EE + t] = acc[g] + bias;
    }
}

extern "C" void kernel_launch(void* const* d_in, const int* in_sizes, int n_in,
                              void* d_out, int out_size, void* d_ws, size_t ws_size,
                              hipStream_t stream) {
    const float* x  = (const float*)d_in[0];
    const float* mw = (const float*)d_in[1];
    const float* mb = (const float*)d_in[2];
    const float* pw = (const float*)d_in[3];
    const float* pb = (const float*)d_in[4];
    float* out = (float*)d_out;
    float* pwT = (float*)d_ws;   // 147*384*4 = 225 KB scratch

    const int B = in_sizes[0] / (CIN * HH * WW);   // 64

    transpose_pw_kernel<<<(EE * KK + 255) / 256, 256, 0, stream>>>(pw, pwT);
    metric_patch_kernel<<<B * 64, TB, 0, stream>>>(x, mw, mb, pwT, pb, out);
}